// Round 5
// baseline (2387.143 us; speedup 1.0000x reference)
//
#include <hip/hip_runtime.h>

#define Bsz  2048
#define Tlen 512
#define Din  32
#define Hd   64
#define BT   16            // batches per tile (MFMA N=16)
#define HS   72            // h-tile row stride in f16 elems
#define BUFE 2048          // f16 elems per h LDS buffer
#define RSLOT 16           // ring slots (steps) per tile
#define RCH   8            // steps per flag update (chunk)
#define RING_BYTES (128 * RSLOT * BT * Hd * 2)   // 4 MB
#define SPIN_MAX (1 << 13) // bounded spin: pathological case -> fast wrong answer, never a timeout
// fallback (mono) kernel staging params
#define CHUNK 16
#define NCHUNK (Tlen / CHUNK)
#define XSTRH 1040
#define XBUFB (BT * XSTRH)

typedef _Float16 half8 __attribute__((ext_vector_type(8)));
typedef _Float16 half4 __attribute__((ext_vector_type(4)));
typedef float    f32x4 __attribute__((ext_vector_type(4)));

#define MFMA(a, b, c) __builtin_amdgcn_mfma_f32_16x16x32_f16((a), (b), (c), 0, 0, 0)

__device__ __forceinline__ half8 load8s(const float* p, float s) {
    half8 r;
#pragma unroll
    for (int j = 0; j < 8; ++j) r[j] = (_Float16)(p[j] * s);
    return r;
}
__device__ __forceinline__ half8 cvt8(float4 a, float4 b) {
    half8 r;
    r[0] = (_Float16)a.x; r[1] = (_Float16)a.y; r[2] = (_Float16)a.z; r[3] = (_Float16)a.w;
    r[4] = (_Float16)b.x; r[5] = (_Float16)b.y; r[6] = (_Float16)b.z; r[7] = (_Float16)b.w;
    return r;
}

// weights pre-scaled by -log2(e) (r,z) and -2*log2(e) (n). With E = 2^(scaled):
//   sigma(raw) = 1/(1+E),  tanh(raw_n) = (1-E_n)/(1+E_n)
// GRU update folds to ONE rcp:  h' = [E_z(1-E_n) + h(1+E_n)] / [(1+E_z)(1+E_n)]
__device__ __forceinline__ half4 gate_upd(const f32x4& gr, const f32x4& gz,
                                          const f32x4& anx, const f32x4& anh,
                                          float hst[4]) {
    half4 pk;
#pragma unroll
    for (int r = 0; r < 4; ++r) {
        float Er = __builtin_amdgcn_exp2f(gr[r]);
        float rr = __builtin_amdgcn_rcpf(1.0f + Er);
        float yy = anx[r] + rr * anh[r];
        float En = __builtin_amdgcn_exp2f(yy);
        float Ez = __builtin_amdgcn_exp2f(gz[r]);
        float num = Ez * (1.0f - En) + hst[r] * (1.0f + En);
        float den = (1.0f + Ez) * (1.0f + En);
        hst[r] = num * __builtin_amdgcn_rcpf(den);
        pk[r] = (_Float16)hst[r];
    }
    return pk;
}

// lgkm-only workgroup barrier: LDS producer/consumer ordering without draining
// vmcnt (ring stores / prefetch loads stay in flight across steps — T4).
#define WG_BARRIER()                                           \
  do {                                                         \
    asm volatile("s_waitcnt lgkmcnt(0)" ::: "memory");         \
    __builtin_amdgcn_s_barrier();                              \
    __builtin_amdgcn_sched_barrier(0);                         \
  } while (0)

// ===========================================================================
// Producer/consumer kernel: 256 blocks x 256 threads (4 waves), all co-resident
// (256 blocks <= 1 block/CU at launch_bounds(256,2); co-residency structural).
//   role 0 (producer): layer-1 recurrence for one 16-batch tile; h1[t] streamed
//     into a 16-slot global ring; flag released every RCH steps. Release
//     protocol: ALL waves s_waitcnt vmcnt(0) -> s_barrier -> tid0 agent-scope
//     atomic release (block's stores all sit in one XCD L2 -> wbl2 covers them).
//   role 1 (consumer): layer-2 recurrence; h1 read from ring with DISTANCE-2
//     register prefetch gated by acquire-polled flag; h2 in LDS dbuf; FC head.
// Bounded-buffer guard: producer waits cf >= I-7 before overwriting (covers
// consumer's 2-ahead reads). All spins bounded by SPIN_MAX (no timeout ever;
// pathological case degrades to a fast wrong answer, not a hang).
// ===========================================================================
__global__ __launch_bounds__(256, 2)
void gru_pc(const float* __restrict__ x,
            const float* __restrict__ Wih0, const float* __restrict__ Whh0,
            const float* __restrict__ bih0, const float* __restrict__ bhh0,
            const float* __restrict__ Wih1, const float* __restrict__ Whh1,
            const float* __restrict__ bih1, const float* __restrict__ bhh1,
            const float* __restrict__ fcw,  const float* __restrict__ fcb,
            void* __restrict__ ws, float* __restrict__ out)
{
    __shared__ _Float16 arena[2 * BUFE];   // h dbuf (h1 for producer, h2 for consumer)
    __shared__ float hfin[BT][Hd];         // consumer only

    const int tid  = threadIdx.x;
    const int lane = tid & 63;
    const int wg   = tid >> 6;             // wave: 16 gate-cols each
    const int blk  = blockIdx.x;
    const int tile = (blk >> 4) * 8 + (blk & 7);   // pair (p,c) = (blk, blk+8):
    const int role = (blk >> 3) & 1;               // same XCD if rr dispatch (perf only)
    const int m    = lane & 15;
    const int quad = lane >> 4;
    const int col  = (wg << 4) + m;
    const int gc   = (wg << 4) + (quad << 2);
    const int b0   = tile << 4;

    _Float16* ringT = (_Float16*)ws + (size_t)tile * (RSLOT * BT * Hd);
    int* flg = (int*)((char*)ws + RING_BYTES);
    int* pf  = flg + tile;           // producer progress (steps written)
    int* cf  = flg + 128 + tile;     // consumer progress (steps consumed)

    const float sRZ = -1.44269504f;
    const float sN  = -2.88539008f;
    const int rdoff = m * HS + quad * 8;       // LDS B-frag read
    const int wroff = m * HS + gc;             // LDS C write
    const int wrg   = m * Hd + gc;             // ring write (elems)
    const int rdg   = m * Hd + quad * 8;       // ring read  (elems)
    float hst[4] = {0.f, 0.f, 0.f, 0.f};

    if (role == 0) {
        // ---------------- PRODUCER: layer 1 ----------------
        half8 wx0, wx1, wx2, wh[2][3];
        f32x4 brz0v, brz1v, binv, bhnv;
        wx0 = load8s(Wih0 + (      col) * Din + quad * 8, sRZ);
        wx1 = load8s(Wih0 + ( 64 + col) * Din + quad * 8, sRZ);
        wx2 = load8s(Wih0 + (128 + col) * Din + quad * 8, sN);
#pragma unroll
        for (int kb = 0; kb < 2; ++kb) {
            wh[kb][0] = load8s(Whh0 + (      col) * Hd + kb * 32 + quad * 8, sRZ);
            wh[kb][1] = load8s(Whh0 + ( 64 + col) * Hd + kb * 32 + quad * 8, sRZ);
            wh[kb][2] = load8s(Whh0 + (128 + col) * Hd + kb * 32 + quad * 8, sN);
        }
#pragma unroll
        for (int r = 0; r < 4; ++r) {
            brz0v[r] = sRZ * (bih0[gc + r] + bhh0[gc + r]);
            brz1v[r] = sRZ * (bih0[64 + gc + r] + bhh0[64 + gc + r]);
            binv[r]  = sN * bih0[128 + gc + r];
            bhnv[r]  = sN * bhh0[128 + gc + r];
        }
        const float* xgp = x + (size_t)(b0 + m) * (Tlen * Din) + quad * 8;
        float4 x0a, x0b, x1a, x1b;         // 2-step parity prefetch
        x0a = *(const float4*)(xgp);        x0b = *(const float4*)(xgp + 4);
        x1a = *(const float4*)(xgp + Din);  x1b = *(const float4*)(xgp + Din + 4);
        int consv = 0;

#define STEP_P(I, RO, WO, xa_, xb_)                                              \
  do {                                                                           \
    const _Float16* s1 = arena + (RO) + rdoff;                                   \
    half8 bh0 = *(const half8*)s1;                                               \
    half8 bh1 = *(const half8*)(s1 + 32);                                        \
    half8 ax = cvt8(xa_, xb_);                                                   \
    { const int nx = ((I) + 2 < Tlen) ? (I) + 2 : Tlen - 1;                      \
      const float* p = xgp + (size_t)nx * Din;                                   \
      xa_ = *(const float4*)p; xb_ = *(const float4*)(p + 4); }                  \
    f32x4 arx = brz0v, azx = brz1v, anx = binv;                                  \
    f32x4 arh = {0.f,0.f,0.f,0.f}, azh = {0.f,0.f,0.f,0.f}, anh = bhnv;          \
    arh = MFMA(wh[0][0], bh0, arh); arh = MFMA(wh[1][0], bh1, arh);              \
    azh = MFMA(wh[0][1], bh0, azh); azh = MFMA(wh[1][1], bh1, azh);              \
    anh = MFMA(wh[0][2], bh0, anh); anh = MFMA(wh[1][2], bh1, anh);              \
    arx = MFMA(wx0, ax, arx);                                                    \
    azx = MFMA(wx1, ax, azx);                                                    \
    anx = MFMA(wx2, ax, anx);                                                    \
    f32x4 gr = arx + arh, gz = azx + azh;                                        \
    half4 pk = gate_upd(gr, gz, anx, anh, hst);                                  \
    *(half4*)(arena + (WO) + wroff) = pk;                                        \
    *(half4*)(ringT + ((I) & (RSLOT - 1)) * (BT * Hd) + wrg) = pk;               \
    if (((I) & (RCH - 1)) == (RCH - 1))                                          \
      asm volatile("s_waitcnt vmcnt(0)" ::: "memory");  /* all waves: ring drained */ \
    WG_BARRIER();                                                                \
    if (((I) & (RCH - 1)) == (RCH - 1)) {                                        \
      if (tid == 0)                                                              \
        __hip_atomic_store(pf, (I) + 1, __ATOMIC_RELEASE,                        \
                           __HIP_MEMORY_SCOPE_AGENT);                            \
      if ((I) + 1 < Tlen && (I) - (RSLOT - RCH - 1) > 0) {                       \
        const int need = (I) - (RSLOT - RCH - 1);       /* ring-full guard */    \
        int kc = consv;                                                          \
        for (int sp = 0; kc < need && sp < SPIN_MAX; ++sp) {                     \
          if (lane == 0)                                                         \
            kc = __hip_atomic_load(cf, __ATOMIC_ACQUIRE,                         \
                                   __HIP_MEMORY_SCOPE_AGENT);                    \
          kc = __builtin_amdgcn_readfirstlane(kc);                               \
          if (kc < need) __builtin_amdgcn_s_sleep(8);                            \
        }                                                                        \
        consv = kc;                                                              \
      }                                                                          \
    }                                                                            \
  } while (0)

        // peel I=0: h1[-1]=0, h-side MFMAs skipped
        {
            half8 ax = cvt8(x0a, x0b);
            { const float* p = xgp + 2 * Din;
              x0a = *(const float4*)p; x0b = *(const float4*)(p + 4); }
            f32x4 gr = brz0v, gz = brz1v, anx = binv, anh = bhnv;
            gr  = MFMA(wx0, ax, gr);
            gz  = MFMA(wx1, ax, gz);
            anx = MFMA(wx2, ax, anx);
            half4 pk = gate_upd(gr, gz, anx, anh, hst);
            *(half4*)(arena + 0 + wroff) = pk;
            *(half4*)(ringT + 0 + wrg) = pk;
            WG_BARRIER();
        }
        for (int i = 1; i + 1 < Tlen; i += 2) {
            STEP_P(i,     0,    BUFE, x1a, x1b);
            STEP_P(i + 1, BUFE, 0,    x0a, x0b);
        }
        STEP_P(Tlen - 1, 0, BUFE, x1a, x1b);   // releases pf=512
#undef STEP_P
    } else {
        // ---------------- CONSUMER: layer 2 + FC head ----------------
        half8 wx[2][3], wh[2][3];
        f32x4 brz0v, brz1v, binv, bhnv;
#pragma unroll
        for (int kb = 0; kb < 2; ++kb) {
            wx[kb][0] = load8s(Wih1 + (      col) * Hd + kb * 32 + quad * 8, sRZ);
            wx[kb][1] = load8s(Wih1 + ( 64 + col) * Hd + kb * 32 + quad * 8, sRZ);
            wx[kb][2] = load8s(Wih1 + (128 + col) * Hd + kb * 32 + quad * 8, sN);
            wh[kb][0] = load8s(Whh1 + (      col) * Hd + kb * 32 + quad * 8, sRZ);
            wh[kb][1] = load8s(Whh1 + ( 64 + col) * Hd + kb * 32 + quad * 8, sRZ);
            wh[kb][2] = load8s(Whh1 + (128 + col) * Hd + kb * 32 + quad * 8, sN);
        }
#pragma unroll
        for (int r = 0; r < 4; ++r) {
            brz0v[r] = sRZ * (bih1[gc + r] + bhh1[gc + r]);
            brz1v[r] = sRZ * (bih1[64 + gc + r] + bhh1[64 + gc + r]);
            binv[r]  = sN * bih1[128 + gc + r];
            bhnv[r]  = sN * bhh1[128 + gc + r];
        }
        for (int idx = tid; idx < 2 * BUFE; idx += 256) arena[idx] = (_Float16)0.f;
        __syncthreads();
        int known = 0;

#define POLLP(NEED)                                                              \
  if (known < (NEED)) {                                                          \
    int kc = known;                                                              \
    for (int sp = 0; kc < (NEED) && sp < SPIN_MAX; ++sp) {                       \
      if (lane == 0)                                                             \
        kc = __hip_atomic_load(pf, __ATOMIC_ACQUIRE,                             \
                               __HIP_MEMORY_SCOPE_AGENT);                        \
      kc = __builtin_amdgcn_readfirstlane(kc);                                   \
      if (kc < (NEED)) __builtin_amdgcn_s_sleep(8);                              \
    }                                                                            \
    known = kc;                                                                  \
  }

// step J: consume h1[J] from (bxa,bxb); afterwards refill (bxa,bxb) with
// h1[J+2] (distance-2 prefetch -> a full step of latency slack for the
// cross-L2 ring read). POLLP is a cached register check in steady state.
#define STEP_C(J, RO, WO, bxa, bxb)                                              \
  do {                                                                           \
    const _Float16* s2 = arena + (RO) + rdoff;            /* h2[J-1] */          \
    half8 bh0 = *(const half8*)s2;                                               \
    half8 bh1 = *(const half8*)(s2 + 32);                                        \
    f32x4 arx = brz0v, azx = brz1v, anx = binv;                                  \
    f32x4 arh = {0.f,0.f,0.f,0.f}, azh = {0.f,0.f,0.f,0.f}, anh = bhnv;          \
    arx = MFMA(wx[0][0], bxa, arx); arx = MFMA(wx[1][0], bxb, arx);              \
    azx = MFMA(wx[0][1], bxa, azx); azx = MFMA(wx[1][1], bxb, azx);              \
    anx = MFMA(wx[0][2], bxa, anx); anx = MFMA(wx[1][2], bxb, anx);              \
    arh = MFMA(wh[0][0], bh0, arh); arh = MFMA(wh[1][0], bh1, arh);              \
    azh = MFMA(wh[0][1], bh0, azh); azh = MFMA(wh[1][1], bh1, azh);              \
    anh = MFMA(wh[0][2], bh0, anh); anh = MFMA(wh[1][2], bh1, anh);              \
    if ((J) + 2 < Tlen) {                                                        \
      POLLP((J) + 3);                                                            \
      const _Float16* gp = ringT + (((J) + 2) & (RSLOT - 1)) * (BT * Hd) + rdg;  \
      bxa = *(const half8*)gp;                                                   \
      bxb = *(const half8*)(gp + 32);                                            \
    }                                                                            \
    f32x4 gr = arx + arh, gz = azx + azh;                                        \
    half4 pk = gate_upd(gr, gz, anx, anh, hst);                                  \
    *(half4*)(arena + (WO) + wroff) = pk;                                        \
    if ((J) == Tlen - 1) {                                                       \
      f32x4 fv;                                                                  \
      for (int r = 0; r < 4; ++r) fv[r] = hst[r];                                \
      *(f32x4*)(&hfin[m][gc]) = fv;                                              \
    }                                                                            \
    WG_BARRIER();                                                                \
    if (((J) & (RCH - 1)) == (RCH - 1) && tid == 0)                              \
      __hip_atomic_store(cf, (J) + 1, __ATOMIC_RELEASE,                          \
                         __HIP_MEMORY_SCOPE_AGENT);                              \
  } while (0)

        half8 p0a, p0b, p1a, p1b;
        POLLP(1);
        {   // h1[0] -> parity-0 bufs
            const _Float16* gp = ringT + rdg;
            p0a = *(const half8*)gp;
            p0b = *(const half8*)(gp + 32);
        }
        POLLP(2);
        {   // h1[1] -> parity-1 bufs
            const _Float16* gp = ringT + (BT * Hd) + rdg;
            p1a = *(const half8*)gp;
            p1b = *(const half8*)(gp + 32);
        }
        STEP_C(0, BUFE, 0, p0a, p0b);
        for (int j = 1; j + 1 < Tlen; j += 2) {
            STEP_C(j,     0,    BUFE, p1a, p1b);
            STEP_C(j + 1, BUFE, 0,    p0a, p0b);
        }
        STEP_C(Tlen - 1, 0, BUFE, p1a, p1b);
#undef STEP_C
#undef POLLP
        __syncthreads();
        if (tid < BT) {                            // FC head
            float acc = fcb[0];
            for (int c = 0; c < Hd; ++c) acc += hfin[tid][c] * fcw[c];
            out[b0 + tid] = acc;
        }
    }
}

// ===========================================================================
// Fallback (known-good r1 kernel, 297 us): used only if ws_size is too small.
// ===========================================================================
__device__ __forceinline__ void gate_update_m(const f32x4& gr, const f32x4& gz,
                                              const f32x4& anx, const f32x4& anh,
                                              float hst[4], _Float16* dst, bool wr) {
    half4 pk;
#pragma unroll
    for (int r = 0; r < 4; ++r) {
        float Er = __builtin_amdgcn_exp2f(gr[r]);
        float rr = __builtin_amdgcn_rcpf(1.0f + Er);
        float yy = anx[r] + rr * anh[r];
        float En = __builtin_amdgcn_exp2f(yy);
        float Ez = __builtin_amdgcn_exp2f(gz[r]);
        float num = Ez * (1.0f - En) + hst[r] * (1.0f + En);
        float den = (1.0f + Ez) * (1.0f + En);
        hst[r] = num * __builtin_amdgcn_rcpf(den);
        pk[r] = (_Float16)hst[r];
    }
    if (wr) *(half4*)dst = pk;
}

__global__ __launch_bounds__(512, 2)
void gru_mono(const float* __restrict__ x,
              const float* __restrict__ Wih0, const float* __restrict__ Whh0,
              const float* __restrict__ bih0, const float* __restrict__ bhh0,
              const float* __restrict__ Wih1, const float* __restrict__ Whh1,
              const float* __restrict__ bih1, const float* __restrict__ bhh1,
              const float* __restrict__ fcw,  const float* __restrict__ fcb,
              float* __restrict__ out)
{
    __shared__ _Float16 arena[4 * BUFE];
    __shared__ __attribute__((aligned(16))) char xstage[2 * XBUFB];
    __shared__ float hfin[BT][Hd];

    const int tid  = threadIdx.x;
    const int lane = tid & 63;
    const int wave = tid >> 6;
    const int grp  = wave >> 2;
    const int wg   = wave & 3;
    const int m    = lane & 15;
    const int quad = lane >> 4;
    const int col  = (wg << 4) + m;
    const int gc   = (wg << 4) + (quad << 2);
    const int b0   = blockIdx.x << 4;

    for (int idx = tid; idx < 4 * BUFE; idx += 512) arena[idx] = (_Float16)0.f;

    const int sb    = (wave << 1) + (lane >> 5);
    const int st    = (lane & 31) >> 1;
    const int sdh   = lane & 1;
    const float* xgp = x + (size_t)(b0 + sb) * (Tlen * Din) + st * Din + sdh * 16;
    const int swoff = sb * XSTRH + st * 64 + sdh * 32;

    float4 xh0, xh1, xh2, xh3;
    {
        const float* p = xgp;
        xh0 = *(const float4*)p;       xh1 = *(const float4*)(p + 4);
        xh2 = *(const float4*)(p + 8); xh3 = *(const float4*)(p + 12);
        char* wp = xstage + swoff;
        *(half8*)wp        = cvt8(xh0, xh1);
        *(half8*)(wp + 16) = cvt8(xh2, xh3);
    }
    {
        const float* p = xgp + CHUNK * Din;
        xh0 = *(const float4*)p;       xh1 = *(const float4*)(p + 4);
        xh2 = *(const float4*)(p + 8); xh3 = *(const float4*)(p + 12);
        char* wp = xstage + XBUFB + swoff;
        *(half8*)wp        = cvt8(xh0, xh1);
        *(half8*)(wp + 16) = cvt8(xh2, xh3);
    }
    {
        const float* p = xgp + 2 * CHUNK * Din;
        xh0 = *(const float4*)p;       xh1 = *(const float4*)(p + 4);
        xh2 = *(const float4*)(p + 8); xh3 = *(const float4*)(p + 12);
    }

    const float sRZ = -1.44269504f;
    const float sN  = -2.88539008f;
    half8 wx[2][3], wh[2][3];
    f32x4 brz0v, brz1v, binv, bhnv;

    if (grp == 0) {
        wx[0][0] = load8s(Wih0 + (      col) * Din + quad * 8, sRZ);
        wx[0][1] = load8s(Wih0 + ( 64 + col) * Din + quad * 8, sRZ);
        wx[0][2] = load8s(Wih0 + (128 + col) * Din + quad * 8, sN);
#pragma unroll
        for (int kb = 0; kb < 2; ++kb) {
            wh[kb][0] = load8s(Whh0 + (      col) * Hd + kb * 32 + quad * 8, sRZ);
            wh[kb][1] = load8s(Whh0 + ( 64 + col) * Hd + kb * 32 + quad * 8, sRZ);
            wh[kb][2] = load8s(Whh0 + (128 + col) * Hd + kb * 32 + quad * 8, sN);
        }
#pragma unroll
        for (int r = 0; r < 4; ++r) {
            brz0v[r] = sRZ * (bih0[gc + r] + bhh0[gc + r]);
            brz1v[r] = sRZ * (bih0[64 + gc + r] + bhh0[64 + gc + r]);
            binv[r]  = sN * bih0[128 + gc + r];
            bhnv[r]  = sN * bhh0[128 + gc + r];
        }
    } else {
#pragma unroll
        for (int kb = 0; kb < 2; ++kb) {
            wx[kb][0] = load8s(Wih1 + (      col) * Hd + kb * 32 + quad * 8, sRZ);
            wx[kb][1] = load8s(Wih1 + ( 64 + col) * Hd + kb * 32 + quad * 8, sRZ);
            wx[kb][2] = load8s(Wih1 + (128 + col) * Hd + kb * 32 + quad * 8, sN);
            wh[kb][0] = load8s(Whh1 + (      col) * Hd + kb * 32 + quad * 8, sRZ);
            wh[kb][1] = load8s(Whh1 + ( 64 + col) * Hd + kb * 32 + quad * 8, sRZ);
            wh[kb][2] = load8s(Whh1 + (128 + col) * Hd + kb * 32 + quad * 8, sN);
        }
#pragma unroll
        for (int r = 0; r < 4; ++r) {
            brz0v[r] = sRZ * (bih1[gc + r] + bhh1[gc + r]);
            brz1v[r] = sRZ * (bih1[64 + gc + r] + bhh1[64 + gc + r]);
            binv[r]  = sN * bih1[128 + gc + r];
            bhnv[r]  = sN * bhh1[128 + gc + r];
        }
    }

    const int rdoff  = m * HS + quad * 8;
    const int xroffH = m * XSTRH + quad * 16;
    const int wroff  = m * HS + gc;
    float hst[4] = {0.f, 0.f, 0.f, 0.f};
    half8 ax;
    __syncthreads();

    if (grp == 0) ax = *(const half8*)(xstage + xroffH);

#define STEPM(I, RO, WO)                                                         \
  do {                                                                           \
    if (grp == 0) {                                                              \
      const _Float16* s1 = arena + (RO) + rdoff;                                 \
      half8 bh0 = *(const half8*)s1;                                             \
      half8 bh1 = *(const half8*)(s1 + 32);                                      \
      f32x4 arx = brz0v, azx = brz1v, anx = binv;                                \
      f32x4 arh = {0.f,0.f,0.f,0.f}, azh = {0.f,0.f,0.f,0.f};                    \
      f32x4 anh = bhnv;                                                          \
      arh = MFMA(wh[0][0], bh0, arh); arh = MFMA(wh[1][0], bh1, arh);            \
      azh = MFMA(wh[0][1], bh0, azh); azh = MFMA(wh[1][1], bh1, azh);            \
      anh = MFMA(wh[0][2], bh0, anh); anh = MFMA(wh[1][2], bh1, anh);            \
      arx = MFMA(wx[0][0], ax, arx);                                             \
      azx = MFMA(wx[0][1], ax, azx);                                             \
      anx = MFMA(wx[0][2], ax, anx);                                             \
      f32x4 gr = arx + arh, gz = azx + azh;                                      \
      gate_update_m(gr, gz, anx, anh, hst, arena + (WO) + wroff, true);          \
      { const int nx = ((I) + 1 < Tlen) ? (I) + 1 : (I);                         \
        ax = *(const half8*)(xstage + ((nx >> 4) & 1) * XBUFB                    \
                             + (nx & 15) * 64 + xroffH); }                       \
    } else {                                                                     \
      const _Float16* s1 = arena + (RO) + rdoff;                                 \
      const _Float16* s2 = s1 + 2 * BUFE;                                        \
      half8 bx0 = *(const half8*)s1;                                             \
      half8 bx1 = *(const half8*)(s1 + 32);                                      \
      half8 bh0 = *(const half8*)s2;                                             \
      half8 bh1 = *(const half8*)(s2 + 32);                                      \
      f32x4 arx = brz0v, azx = brz1v, anx = binv;                                \
      f32x4 arh = {0.f,0.f,0.f,0.f}, azh = {0.f,0.f,0.f,0.f};                    \
      f32x4 anh = bhnv;                                                          \
      arx = MFMA(wx[0][0], bx0, arx); arx = MFMA(wx[1][0], bx1, arx);            \
      azx = MFMA(wx[0][1], bx0, azx); azx = MFMA(wx[1][1], bx1, azx);            \
      anx = MFMA(wx[0][2], bx0, anx); anx = MFMA(wx[1][2], bx1, anx);            \
      arh = MFMA(wh[0][0], bh0, arh); arh = MFMA(wh[1][0], bh1, arh);            \
      azh = MFMA(wh[0][1], bh0, azh); azh = MFMA(wh[1][1], bh1, azh);            \
      anh = MFMA(wh[0][2], bh0, anh); anh = MFMA(wh[1][2], bh1, anh);            \
      f32x4 gr = arx + arh, gz = azx + azh;                                      \
      gate_update_m(gr, gz, anx, anh, hst, arena + 2 * BUFE + (WO) + wroff,      \
                    true);                                                       \
    }                                                                            \
    __syncthreads();                                                             \
  } while (0)

    if (grp == 0) {
        f32x4 gr = brz0v, gz = brz1v, anx = binv, anh = bhnv;
        gr  = MFMA(wx[0][0], ax, gr);
        gz  = MFMA(wx[0][1], ax, gz);
        anx = MFMA(wx[0][2], ax, anx);
        gate_update_m(gr, gz, anx, anh, hst, arena + 0 + wroff, true);
        ax = *(const half8*)(xstage + 1 * 64 + xroffH);
    }
    __syncthreads();

    for (int i = 1; i + 1 < Tlen; i += 2) {
        STEPM(i, 0, BUFE);
        if (((i + 1) & (CHUNK - 1)) == 0) {
            const int k = (i + 1) >> 4;
            if (k + 1 < NCHUNK) {
                char* wp = xstage + ((k + 1) & 1) * XBUFB + swoff;
                *(half8*)wp        = cvt8(xh0, xh1);
                *(half8*)(wp + 16) = cvt8(xh2, xh3);
            }
            if (k + 2 < NCHUNK) {
                const float* p = xgp + (size_t)(k + 2) * (CHUNK * Din);
                xh0 = *(const float4*)p;       xh1 = *(const float4*)(p + 4);
                xh2 = *(const float4*)(p + 8); xh3 = *(const float4*)(p + 12);
            }
        }
        STEPM(i + 1, BUFE, 0);
    }
    STEPM(Tlen - 1, 0, BUFE);

    if (grp == 1) {
        const _Float16* s1 = arena + BUFE + rdoff;
        const _Float16* s2 = s1 + 2 * BUFE;
        half8 bx0 = *(const half8*)s1;
        half8 bx1 = *(const half8*)(s1 + 32);
        half8 bh0 = *(const half8*)s2;
        half8 bh1 = *(const half8*)(s2 + 32);
        f32x4 arx = brz0v, azx = brz1v, anx = binv;
        f32x4 arh = {0.f,0.f,0.f,0.f}, azh = {0.f,0.f,0.f,0.f};
        f32x4 anh = bhnv;
        arx = MFMA(wx[0][0], bx0, arx); arx = MFMA(wx[1][0], bx1, arx);
        azx = MFMA(wx[0][1], bx0, azx); azx = MFMA(wx[1][1], bx1, azx);
        anx = MFMA(wx[0][2], bx0, anx); anx = MFMA(wx[1][2], bx1, anx);
        arh = MFMA(wh[0][0], bh0, arh); arh = MFMA(wh[1][0], bh1, arh);
        azh = MFMA(wh[0][1], bh0, azh); azh = MFMA(wh[1][1], bh1, azh);
        anh = MFMA(wh[0][2], bh0, anh); anh = MFMA(wh[1][2], bh1, anh);
        f32x4 gr = arx + arh, gz = azx + azh;
        gate_update_m(gr, gz, anx, anh, hst, nullptr, false);
        f32x4 fv;
#pragma unroll
        for (int r = 0; r < 4; ++r) fv[r] = hst[r];
        *(f32x4*)(&hfin[m][gc]) = fv;
    }
    __syncthreads();
    if (tid < BT) {
        float acc = fcb[0];
        for (int c = 0; c < Hd; ++c) acc += hfin[tid][c] * fcw[c];
        out[b0 + tid] = acc;
    }
#undef STEPM
}

extern "C" void kernel_launch(void* const* d_in, const int* in_sizes, int n_in,
                              void* d_out, int out_size, void* d_ws, size_t ws_size,
                              hipStream_t stream) {
    if (d_ws && ws_size >= (size_t)RING_BYTES + 1024) {
        // zero the flag region each launch (stream-ordered, graph-capture-safe)
        hipMemsetAsync((char*)d_ws + RING_BYTES, 0, 1024, stream);
        gru_pc<<<dim3(256), dim3(256), 0, stream>>>(
            (const float*)d_in[0],
            (const float*)d_in[1], (const float*)d_in[2],
            (const float*)d_in[3], (const float*)d_in[4],
            (const float*)d_in[5], (const float*)d_in[6],
            (const float*)d_in[7], (const float*)d_in[8],
            (const float*)d_in[9], (const float*)d_in[10],
            d_ws, (float*)d_out);
    } else {
        gru_mono<<<dim3(Bsz / BT), dim3(512), 0, stream>>>(
            (const float*)d_in[0],
            (const float*)d_in[1], (const float*)d_in[2],
            (const float*)d_in[3], (const float*)d_in[4],
            (const float*)d_in[5], (const float*)d_in[6],
            (const float*)d_in[7], (const float*)d_in[8],
            (const float*)d_in[9], (const float*)d_in[10],
            (float*)d_out);
    }
}

// Round 6
// 535.752 us; speedup vs baseline: 4.4557x; 4.4557x over previous
//
#include <hip/hip_runtime.h>

#define Bsz  2048
#define Tlen 512
#define Din  32
#define Hd   64
#define BT   16            // batches per block (MFMA N=16)
#define HS   72            // h row stride in f16 elems (144B, 16B-aligned, bank-spread)
#define SLOT (BT * HS)     // one h snapshot = 1152 f16 = 2304 B
#define SPINB (1 << 14)    // bounded spin: bug -> fast wrong answer, never a hang

typedef _Float16 half8 __attribute__((ext_vector_type(8)));
typedef _Float16 half4 __attribute__((ext_vector_type(4)));
typedef float    f32x4 __attribute__((ext_vector_type(4)));

#define MFMA(a, b, c) __builtin_amdgcn_mfma_f32_16x16x32_f16((a), (b), (c), 0, 0, 0)

__device__ __forceinline__ half8 load8s(const float* p, float s) {
    half8 r;
#pragma unroll
    for (int j = 0; j < 8; ++j) r[j] = (_Float16)(p[j] * s);
    return r;
}
__device__ __forceinline__ half8 cvt8(float4 a, float4 b) {
    half8 r;
    r[0] = (_Float16)a.x; r[1] = (_Float16)a.y; r[2] = (_Float16)a.z; r[3] = (_Float16)a.w;
    r[4] = (_Float16)b.x; r[5] = (_Float16)b.y; r[6] = (_Float16)b.z; r[7] = (_Float16)b.w;
    return r;
}

// weights pre-scaled by -log2(e) (r,z) and -2*log2(e) (n). With E = 2^(scaled):
//   sigma(raw) = 1/(1+E),  tanh(raw_n) = (1-E_n)/(1+E_n)
// GRU update folds to ONE rcp:  h' = [E_z(1-E_n) + h(1+E_n)] / [(1+E_z)(1+E_n)]
__device__ __forceinline__ half4 gate_upd(const f32x4& gr, const f32x4& gz,
                                          const f32x4& anx, const f32x4& anh,
                                          float hst[4]) {
    half4 pk;
#pragma unroll
    for (int r = 0; r < 4; ++r) {
        float Er = __builtin_amdgcn_exp2f(gr[r]);
        float rr = __builtin_amdgcn_rcpf(1.0f + Er);
        float yy = anx[r] + rr * anh[r];
        float En = __builtin_amdgcn_exp2f(yy);
        float Ez = __builtin_amdgcn_exp2f(gz[r]);
        float num = Ez * (1.0f - En) + hst[r] * (1.0f + En);
        float den = (1.0f + Ez) * (1.0f + En);
        hst[r] = num * __builtin_amdgcn_rcpf(den);
        pk[r] = (_Float16)hst[r];
    }
    return pk;
}

// spin until LDS counter CTR >= TGT, with per-wave cached value CACHE.
// Fast path (cache satisfies) costs nothing. Acquire load (lane 0) +
// readfirstlane broadcast; sched_barrier fences later LDS reads from being
// hoisted above the gate (guide rule #18 analog). Negative/zero TGT = no-op.
#define SPIN_GE(CTR, TGT, CACHE)                                         \
  do {                                                                   \
    if ((CACHE) < (TGT)) {                                               \
      int v_ = (CACHE);                                                  \
      for (int sp_ = 0; v_ < (TGT) && sp_ < SPINB; ++sp_) {              \
        if (lane == 0)                                                   \
          v_ = __hip_atomic_load(&CTR, __ATOMIC_ACQUIRE,                 \
                                 __HIP_MEMORY_SCOPE_WORKGROUP);          \
        v_ = __builtin_amdgcn_readfirstlane(v_);                         \
        if (v_ < (TGT)) __builtin_amdgcn_s_sleep(1);                     \
      }                                                                  \
      (CACHE) = v_;                                                      \
    }                                                                    \
    __builtin_amdgcn_sched_barrier(0);                                   \
  } while (0)

// ===========================================================================
// Barrier-free GRU: 128 blocks x 512 threads. Waves 0-3 = layer-1 (grp0),
// waves 4-7 = layer-2 (grp1). NO s_barrier in the main loop — wave groups
// sync through monotonic LDS counters:
//   c1: grp0 step completions (h1[t] ready for all readers when c1 >= 4(t+1))
//   c2: grp1 step completions (h2 ring internal ordering)
//   u1: grp1 h1-consumption acks (grp0 may overwrite ring slot t&3 with h1[t]
//       once u1 >= 4(t-3), i.e. h1[t-4] fully consumed)
// h1 lives in a 4-slot LDS ring, h2 in a 2-slot ring. The groups drift 1-3
// steps apart, so per-SIMD (1 grp0 + 1 grp1 wave) the LDS/MFMA/trans phases
// interleave instead of colliding post-barrier. Deadlock-free (grp0@t needs
// grp1 >= t-3; grp1@j needs grp0 >= j+1 — no cycle); spins bounded.
// Step 0 needs no peel: ring slots h1[-1], h2[-1] are zero-filled, so the
// h-side MFMAs contribute exactly 0 (bias-only), matching the peeled math.
// ===========================================================================
__global__ __launch_bounds__(512, 2)
void gru_fused(const float* __restrict__ x,
               const float* __restrict__ Wih0, const float* __restrict__ Whh0,
               const float* __restrict__ bih0, const float* __restrict__ bhh0,
               const float* __restrict__ Wih1, const float* __restrict__ Whh1,
               const float* __restrict__ bih1, const float* __restrict__ bhh1,
               const float* __restrict__ fcw,  const float* __restrict__ fcb,
               float* __restrict__ out)
{
    __shared__ _Float16 h1r[4 * SLOT];     // h1 ring (9216 B)
    __shared__ _Float16 h2r[2 * SLOT];     // h2 ring (4608 B)
    __shared__ float hfin[BT][Hd];         // final h2 for FC head
    __shared__ int c1, c2, u1;

    const int tid  = threadIdx.x;
    const int lane = tid & 63;
    const int wave = tid >> 6;
    const int grp  = wave >> 2;            // 0 = layer1, 1 = layer2
    const int wg   = wave & 3;             // 16 gate-cols per wave
    const int m    = lane & 15;            // A row (W row) AND B col (batch)
    const int quad = lane >> 4;            // k-chunk (A/B), col-group (C/D)
    const int col  = (wg << 4) + m;        // W row this lane loads (A-frag)
    const int gc   = (wg << 4) + (quad << 2); // C-frag col base this lane owns
    const int b0   = blockIdx.x << 4;

    // zero h1[-1] slot (3), h2[-1] slot (1), counters; one init barrier only
    for (int idx = tid; idx < SLOT; idx += 512) {
        h1r[3 * SLOT + idx] = (_Float16)0.f;
        h2r[SLOT + idx]     = (_Float16)0.f;
    }
    if (tid == 0) { c1 = 0; c2 = 0; u1 = 0; }

    const float sRZ = -1.44269504f;        // -log2(e)
    const float sN  = -2.88539008f;        // -2*log2(e)
    const int rdoff = m * HS + quad * 8;   // B-frag read: batch m, k = quad*8..
    const int wroff = m * HS + gc;         // C write: batch m, cols gc..gc+3
    float hst[4] = {0.f, 0.f, 0.f, 0.f};

    __syncthreads();                       // init visible; last barrier in kernel

    if (grp == 0) {
        // ---------------- LAYER 1 (waves 0-3) ----------------
        half8 wx0, wx1, wx2, wh[2][3];
        f32x4 brz0v, brz1v, binv, bhnv;
        wx0 = load8s(Wih0 + (      col) * Din + quad * 8, sRZ);
        wx1 = load8s(Wih0 + ( 64 + col) * Din + quad * 8, sRZ);
        wx2 = load8s(Wih0 + (128 + col) * Din + quad * 8, sN);
#pragma unroll
        for (int kb = 0; kb < 2; ++kb) {
            wh[kb][0] = load8s(Whh0 + (      col) * Hd + kb * 32 + quad * 8, sRZ);
            wh[kb][1] = load8s(Whh0 + ( 64 + col) * Hd + kb * 32 + quad * 8, sRZ);
            wh[kb][2] = load8s(Whh0 + (128 + col) * Hd + kb * 32 + quad * 8, sN);
        }
#pragma unroll
        for (int r = 0; r < 4; ++r) {
            brz0v[r] = sRZ * (bih0[gc + r] + bhh0[gc + r]);
            brz1v[r] = sRZ * (bih0[64 + gc + r] + bhh0[64 + gc + r]);
            binv[r]  = sN * bih0[128 + gc + r];
            bhnv[r]  = sN * bhh0[128 + gc + r];
        }
        // x direct from global, 2-step parity register prefetch (r5-proven)
        const float* xgp = x + (size_t)(b0 + m) * (Tlen * Din) + quad * 8;
        float4 x0a, x0b, x1a, x1b;
        x0a = *(const float4*)(xgp);        x0b = *(const float4*)(xgp + 4);
        x1a = *(const float4*)(xgp + Din);  x1b = *(const float4*)(xgp + Din + 4);
        int c1v = 0, u1v = 0;

#define STEP_A(T, xa_, xb_)                                              \
  do {                                                                   \
    SPIN_GE(c1, 4 * (T), c1v);               /* own group: h1[T-1] done */ \
    const _Float16* s1 = h1r + (((T) + 3) & 3) * SLOT + rdoff;           \
    half8 bh0 = *(const half8*)s1;                                       \
    half8 bh1 = *(const half8*)(s1 + 32);                                \
    half8 ax = cvt8(xa_, xb_);                                           \
    { const int nx = ((T) + 2 < Tlen) ? (T) + 2 : Tlen - 1;              \
      const float* p = xgp + (size_t)nx * Din;                           \
      xa_ = *(const float4*)p; xb_ = *(const float4*)(p + 4); }          \
    f32x4 arx = brz0v, azx = brz1v, anx = binv;                          \
    f32x4 arh = {0.f,0.f,0.f,0.f}, azh = {0.f,0.f,0.f,0.f}, anh = bhnv;  \
    arh = MFMA(wh[0][0], bh0, arh); arh = MFMA(wh[1][0], bh1, arh);      \
    azh = MFMA(wh[0][1], bh0, azh); azh = MFMA(wh[1][1], bh1, azh);      \
    anh = MFMA(wh[0][2], bh0, anh); anh = MFMA(wh[1][2], bh1, anh);      \
    arx = MFMA(wx0, ax, arx);                                            \
    azx = MFMA(wx1, ax, azx);                                            \
    anx = MFMA(wx2, ax, anx);                                            \
    f32x4 gr = arx + arh, gz = azx + azh;                                \
    half4 pk = gate_upd(gr, gz, anx, anh, hst);                          \
    SPIN_GE(u1, 4 * ((T) - 3), u1v);         /* ring slot T&3 reusable */ \
    *(half4*)(h1r + ((T) & 3) * SLOT + wroff) = pk;                      \
    asm volatile("s_waitcnt lgkmcnt(0)" ::: "memory");                   \
    if (lane == 0)                                                       \
      __hip_atomic_fetch_add(&c1, 1, __ATOMIC_RELEASE,                   \
                             __HIP_MEMORY_SCOPE_WORKGROUP);              \
  } while (0)

        for (int t = 0; t < Tlen; t += 2) {
            STEP_A(t,     x0a, x0b);
            STEP_A(t + 1, x1a, x1b);
        }
#undef STEP_A
    } else {
        // ---------------- LAYER 2 + FC head (waves 4-7) ----------------
        half8 wx[2][3], wh[2][3];
        f32x4 brz0v, brz1v, binv, bhnv;
#pragma unroll
        for (int kb = 0; kb < 2; ++kb) {
            wx[kb][0] = load8s(Wih1 + (      col) * Hd + kb * 32 + quad * 8, sRZ);
            wx[kb][1] = load8s(Wih1 + ( 64 + col) * Hd + kb * 32 + quad * 8, sRZ);
            wx[kb][2] = load8s(Wih1 + (128 + col) * Hd + kb * 32 + quad * 8, sN);
            wh[kb][0] = load8s(Whh1 + (      col) * Hd + kb * 32 + quad * 8, sRZ);
            wh[kb][1] = load8s(Whh1 + ( 64 + col) * Hd + kb * 32 + quad * 8, sRZ);
            wh[kb][2] = load8s(Whh1 + (128 + col) * Hd + kb * 32 + quad * 8, sN);
        }
#pragma unroll
        for (int r = 0; r < 4; ++r) {
            brz0v[r] = sRZ * (bih1[gc + r] + bhh1[gc + r]);
            brz1v[r] = sRZ * (bih1[64 + gc + r] + bhh1[64 + gc + r]);
            binv[r]  = sN * bih1[128 + gc + r];
            bhnv[r]  = sN * bhh1[128 + gc + r];
        }
        int c1v = 0, c2v = 0;

#define STEP_B(T)                                                        \
  do {                                                                   \
    SPIN_GE(c2, 4 * (T), c2v);               /* own group: h2[T-1] done */ \
    SPIN_GE(c1, 4 * ((T) + 1), c1v);         /* cross group: h1[T] done */ \
    const _Float16* s1 = h1r + ((T) & 3) * SLOT + rdoff;   /* h1[T]   */ \
    const _Float16* s2 = h2r + (((T) + 1) & 1) * SLOT + rdoff; /* h2[T-1] */ \
    half8 bx0 = *(const half8*)s1;                                       \
    half8 bx1 = *(const half8*)(s1 + 32);                                \
    half8 bh0 = *(const half8*)s2;                                       \
    half8 bh1 = *(const half8*)(s2 + 32);                                \
    f32x4 arx = brz0v, azx = brz1v, anx = binv;                          \
    f32x4 arh = {0.f,0.f,0.f,0.f}, azh = {0.f,0.f,0.f,0.f}, anh = bhnv;  \
    arx = MFMA(wx[0][0], bx0, arx); arx = MFMA(wx[1][0], bx1, arx);      \
    azx = MFMA(wx[0][1], bx0, azx); azx = MFMA(wx[1][1], bx1, azx);      \
    anx = MFMA(wx[0][2], bx0, anx); anx = MFMA(wx[1][2], bx1, anx);      \
    arh = MFMA(wh[0][0], bh0, arh); arh = MFMA(wh[1][0], bh1, arh);      \
    azh = MFMA(wh[0][1], bh0, azh); azh = MFMA(wh[1][1], bh1, azh);      \
    anh = MFMA(wh[0][2], bh0, anh); anh = MFMA(wh[1][2], bh1, anh);      \
    asm volatile("s_waitcnt lgkmcnt(0)" ::: "memory");  /* h1 reads done */ \
    if (lane == 0)                                                       \
      __hip_atomic_fetch_add(&u1, 1, __ATOMIC_RELEASE,                   \
                             __HIP_MEMORY_SCOPE_WORKGROUP);              \
    f32x4 gr = arx + arh, gz = azx + azh;                                \
    half4 pk = gate_upd(gr, gz, anx, anh, hst);                          \
    *(half4*)(h2r + ((T) & 1) * SLOT + wroff) = pk;                      \
    if ((T) == Tlen - 1) {                                               \
      f32x4 fv;                                                          \
      for (int r = 0; r < 4; ++r) fv[r] = hst[r];                        \
      *(f32x4*)(&hfin[m][gc]) = fv;                                      \
    }                                                                    \
    asm volatile("s_waitcnt lgkmcnt(0)" ::: "memory");                   \
    if (lane == 0)                                                       \
      __hip_atomic_fetch_add(&c2, 1, __ATOMIC_RELEASE,                   \
                             __HIP_MEMORY_SCOPE_WORKGROUP);              \
  } while (0)

        for (int t = 0; t < Tlen; t += 2) {
            STEP_B(t);
            STEP_B(t + 1);
        }
#undef STEP_B

        // FC head: wave 4 waits for all grp1 waves' hfin (release via c2)
        if (wg == 0) {
            SPIN_GE(c2, 4 * Tlen, c2v);
            if (lane < BT) {
                float acc = fcb[0];
                for (int c = 0; c < Hd; ++c) acc += hfin[lane][c] * fcw[c];
                out[b0 + lane] = acc;
            }
        }
    }
}

extern "C" void kernel_launch(void* const* d_in, const int* in_sizes, int n_in,
                              void* d_out, int out_size, void* d_ws, size_t ws_size,
                              hipStream_t stream) {
    gru_fused<<<dim3(Bsz / BT), dim3(512), 0, stream>>>(
        (const float*)d_in[0],
        (const float*)d_in[1], (const float*)d_in[2],
        (const float*)d_in[3], (const float*)d_in[4],
        (const float*)d_in[5], (const float*)d_in[6],
        (const float*)d_in[7], (const float*)d_in[8],
        (const float*)d_in[9], (const float*)d_in[10],
        (float*)d_out);
}

// Round 8
// 487.591 us; speedup vs baseline: 4.8958x; 1.0988x over previous
//
#include <hip/hip_runtime.h>

#define Bsz  2048
#define Tlen 512
#define Din  32
#define Hd   64
#define BT   16            // batches per block (MFMA N=16)
#define HS   72            // h row stride in f16 elems (144B, 16B-aligned, bank-spread)
#define BUFE 2048          // f16 elems per h buffer (4096 B)

typedef _Float16 half8 __attribute__((ext_vector_type(8)));
typedef _Float16 half4 __attribute__((ext_vector_type(4)));
typedef float    f32x4 __attribute__((ext_vector_type(4)));

#define MFMA(a, b, c) __builtin_amdgcn_mfma_f32_16x16x32_f16((a), (b), (c), 0, 0, 0)

// lgkm-only barrier: orders LDS producer->consumer across waves WITHOUT
// draining vmcnt -- grp0's global x prefetch loads stay in flight across
// barriers (mono's __syncthreads drained them every step). "memory" clobber
// stops compiler moving memory ops across.
#define BARRIER()                                              \
  do {                                                         \
    asm volatile("s_waitcnt lgkmcnt(0)" ::: "memory");         \
    __builtin_amdgcn_s_barrier();                              \
  } while (0)

__device__ __forceinline__ half8 load8s(const float* p, float s) {
    half8 r;
#pragma unroll
    for (int j = 0; j < 8; ++j) r[j] = (_Float16)(p[j] * s);
    return r;
}
__device__ __forceinline__ half8 cvt8(float4 a, float4 b) {
    half8 r;
    r[0] = (_Float16)a.x; r[1] = (_Float16)a.y; r[2] = (_Float16)a.z; r[3] = (_Float16)a.w;
    r[4] = (_Float16)b.x; r[5] = (_Float16)b.y; r[6] = (_Float16)b.z; r[7] = (_Float16)b.w;
    return r;
}

// weights pre-scaled by -log2(e) (r,z) and -2*log2(e) (n). With E = 2^(scaled):
//   sigma(raw) = 1/(1+E),  tanh(raw_n) = (1-E_n)/(1+E_n)
// GRU update folds to ONE rcp:  h' = [E_z(1-E_n) + h(1+E_n)] / [(1+E_z)(1+E_n)]
__device__ __forceinline__ half4 gate_upd(const f32x4& gr, const f32x4& gz,
                                          const f32x4& anx, const f32x4& anh,
                                          float hst[4]) {
    half4 pk;
#pragma unroll
    for (int r = 0; r < 4; ++r) {
        float Er = __builtin_amdgcn_exp2f(gr[r]);
        float rr = __builtin_amdgcn_rcpf(1.0f + Er);
        float yy = anx[r] + rr * anh[r];
        float En = __builtin_amdgcn_exp2f(yy);
        float Ez = __builtin_amdgcn_exp2f(gz[r]);
        float num = Ez * (1.0f - En) + hst[r] * (1.0f + En);
        float den = (1.0f + Ez) * (1.0f + En);
        hst[r] = num * __builtin_amdgcn_rcpf(den);
        pk[r] = (_Float16)hst[r];
    }
    return pk;
}

// ===========================================================================
// Phase-split pipelined GRU: 128 blocks x 512 threads; waves 0-3 = layer 1
// (grp0), waves 4-7 = layer 2 (grp1). Two lgkm-barriers per region (= step).
// Region I:
//  SEG1: grp0: read h1[I-1]@RO, 6 h-MFMA, gates (x-side acc precomputed),
//              write h1[I]@WO              [VALU-heavy tail]
//        grp1: read h2[I-2]@2B+RO, 12 MFMA for step I-1 (h1[I-1] in regs)
//                                          [MFMA-heavy]
//  SEG2: grp0: cvt8 x[I+1], 3 x-MFMA -> xacc for region I+1, refill x regs
//        grp1: gates for step I-1, write h2[I-1]@2B+WO,
//              preload h1[I]@WO -> regs (for region I+1)
// On each SIMD (one grp0 + one grp1 wave) the MFMA and VALU phases are now
// complementary instead of colliding. Same arithmetic as mono at the same
// rounding points. Arena zero-init makes region 0 exact (h-MFMAs on zeros).
// ===========================================================================
__global__ __launch_bounds__(512)
void gru_fused(const float* __restrict__ x,
               const float* __restrict__ Wih0, const float* __restrict__ Whh0,
               const float* __restrict__ bih0, const float* __restrict__ bhh0,
               const float* __restrict__ Wih1, const float* __restrict__ Whh1,
               const float* __restrict__ bih1, const float* __restrict__ bhh1,
               const float* __restrict__ fcw,  const float* __restrict__ fcb,
               float* __restrict__ out)
{
    __shared__ _Float16 arena[4 * BUFE];   // h1 @[0],[B]; h2 @[2B],[3B]
    __shared__ float hfin[BT][Hd];

    const int tid  = threadIdx.x;
    const int lane = tid & 63;
    const int wave = tid >> 6;
    const int grp  = wave >> 2;            // 0 = layer1, 1 = layer2
    const int wg   = wave & 3;             // 16 gate-cols per wave
    const int m    = lane & 15;            // A row (W row) AND B col (batch)
    const int quad = lane >> 4;            // k-chunk (A/B), col-group (C/D)
    const int col  = (wg << 4) + m;        // W row this lane loads (A-frag)
    const int gc   = (wg << 4) + (quad << 2); // C-frag col base this lane owns
    const int b0   = blockIdx.x << 4;

    for (int idx = tid; idx < 4 * BUFE; idx += 512) arena[idx] = (_Float16)0.f;

    const float sRZ = -1.44269504f;        // -log2(e)
    const float sN  = -2.88539008f;        // -2*log2(e)
    const int rdoff = m * HS + quad * 8;   // B-frag read: batch m, k = quad*8..
    const int wroff = m * HS + gc;         // C write: batch m, cols gc..gc+3
    float hst[4] = {0.f, 0.f, 0.f, 0.f};

    // ---- persistent pre-scaled weight A-fragments + biases ----
    half8 wx[2][3], wh[2][3];
    f32x4 brz0v, brz1v, binv, bhnv;
    if (grp == 0) {
        wx[0][0] = load8s(Wih0 + (      col) * Din + quad * 8, sRZ);
        wx[0][1] = load8s(Wih0 + ( 64 + col) * Din + quad * 8, sRZ);
        wx[0][2] = load8s(Wih0 + (128 + col) * Din + quad * 8, sN);
#pragma unroll
        for (int kb = 0; kb < 2; ++kb) {
            wh[kb][0] = load8s(Whh0 + (      col) * Hd + kb * 32 + quad * 8, sRZ);
            wh[kb][1] = load8s(Whh0 + ( 64 + col) * Hd + kb * 32 + quad * 8, sRZ);
            wh[kb][2] = load8s(Whh0 + (128 + col) * Hd + kb * 32 + quad * 8, sN);
        }
#pragma unroll
        for (int r = 0; r < 4; ++r) {
            brz0v[r] = sRZ * (bih0[gc + r] + bhh0[gc + r]);
            brz1v[r] = sRZ * (bih0[64 + gc + r] + bhh0[64 + gc + r]);
            binv[r]  = sN * bih0[128 + gc + r];
            bhnv[r]  = sN * bhh0[128 + gc + r];
        }
    } else {
#pragma unroll
        for (int kb = 0; kb < 2; ++kb) {
            wx[kb][0] = load8s(Wih1 + (      col) * Hd + kb * 32 + quad * 8, sRZ);
            wx[kb][1] = load8s(Wih1 + ( 64 + col) * Hd + kb * 32 + quad * 8, sRZ);
            wx[kb][2] = load8s(Wih1 + (128 + col) * Hd + kb * 32 + quad * 8, sN);
            wh[kb][0] = load8s(Whh1 + (      col) * Hd + kb * 32 + quad * 8, sRZ);
            wh[kb][1] = load8s(Whh1 + ( 64 + col) * Hd + kb * 32 + quad * 8, sRZ);
            wh[kb][2] = load8s(Whh1 + (128 + col) * Hd + kb * 32 + quad * 8, sN);
        }
#pragma unroll
        for (int r = 0; r < 4; ++r) {
            brz0v[r] = sRZ * (bih1[gc + r] + bhh1[gc + r]);
            brz1v[r] = sRZ * (bih1[64 + gc + r] + bhh1[64 + gc + r]);
            binv[r]  = sN * bih1[128 + gc + r];
            bhnv[r]  = sN * bhh1[128 + gc + r];
        }
    }

    // ---- grp0 pipeline state: x parity prefetch + x-side accumulators ----
    const float* xgp = x + (size_t)(b0 + m) * (Tlen * Din) + quad * 8;
    float4 x0a, x0b, x1a, x1b;
    f32x4 xar, xaz, xan;                   // x-side acc (incl. biases) for region I
    if (grp == 0) {
        x0a = *(const float4*)(xgp);        x0b = *(const float4*)(xgp + 4);
        x1a = *(const float4*)(xgp + Din);  x1b = *(const float4*)(xgp + Din + 4);
        half8 ax = cvt8(x0a, x0b);          // x[0]
        xar = brz0v; xar = MFMA(wx[0][0], ax, xar);
        xaz = brz1v; xaz = MFMA(wx[0][1], ax, xaz);
        xan = binv;  xan = MFMA(wx[0][2], ax, xan);
        {   // refill parity-0 with x[2]
            const float* p = xgp + 2 * Din;
            x0a = *(const float4*)p; x0b = *(const float4*)(p + 4);
        }
    }
    // ---- grp1 pipeline state: h1 fragment regs + MFMA accumulators ----
    half8 bx0, bx1;                        // h1[I-1] B-frags (preloaded)
    f32x4 arx, azx, anx, arh, azh, anh;    // 6 accumulators (seg1 -> seg2)

    __syncthreads();                       // arena zero + weights visible

// Region I. RO/WO compile-time. XA/XB: x parity regs used in seg2 (x[I+1]).
// DO1: grp1 compute active (I >= 1). Two lgkm barriers.
#define REGION(I, RO, WO, XA, XB, DO1)                                   \
  do {                                                                   \
    /* ---------------- SEG1 ---------------- */                         \
    if (grp == 0) {                                                      \
      const _Float16* s1 = arena + (RO) + rdoff;                         \
      half8 bh0 = *(const half8*)s1;                                     \
      half8 bh1 = *(const half8*)(s1 + 32);                              \
      f32x4 arh0 = {0.f,0.f,0.f,0.f}, azh0 = {0.f,0.f,0.f,0.f};          \
      f32x4 anh0 = bhnv;                                                 \
      arh0 = MFMA(wh[0][0], bh0, arh0); arh0 = MFMA(wh[1][0], bh1, arh0);\
      azh0 = MFMA(wh[0][1], bh0, azh0); azh0 = MFMA(wh[1][1], bh1, azh0);\
      anh0 = MFMA(wh[0][2], bh0, anh0); anh0 = MFMA(wh[1][2], bh1, anh0);\
      f32x4 gr = xar + arh0, gz = xaz + azh0;                            \
      half4 pk = gate_upd(gr, gz, xan, anh0, hst);                       \
      *(half4*)(arena + (WO) + wroff) = pk;                              \
    } else if (DO1) {                                                    \
      const _Float16* s2 = arena + 2 * BUFE + (RO) + rdoff;              \
      half8 bh0 = *(const half8*)s2;                                     \
      half8 bh1 = *(const half8*)(s2 + 32);                              \
      arx = brz0v; azx = brz1v; anx = binv;                              \
      arh = (f32x4){0.f,0.f,0.f,0.f}; azh = (f32x4){0.f,0.f,0.f,0.f};    \
      anh = bhnv;                                                        \
      arx = MFMA(wx[0][0], bx0, arx); arx = MFMA(wx[1][0], bx1, arx);    \
      azx = MFMA(wx[0][1], bx0, azx); azx = MFMA(wx[1][1], bx1, azx);    \
      anx = MFMA(wx[0][2], bx0, anx); anx = MFMA(wx[1][2], bx1, anx);    \
      arh = MFMA(wh[0][0], bh0, arh); arh = MFMA(wh[1][0], bh1, arh);    \
      azh = MFMA(wh[0][1], bh0, azh); azh = MFMA(wh[1][1], bh1, azh);    \
      anh = MFMA(wh[0][2], bh0, anh); anh = MFMA(wh[1][2], bh1, anh);    \
    }                                                                    \
    BARRIER();                                                           \
    /* ---------------- SEG2 ---------------- */                         \
    if (grp == 0) {                                                      \
      half8 ax = cvt8(XA, XB);             /* x[I+1] */                  \
      { const int nx = ((I) + 3 < Tlen) ? (I) + 3 : Tlen - 1;            \
        const float* p = xgp + (size_t)nx * Din;                         \
        XA = *(const float4*)p; XB = *(const float4*)(p + 4); }          \
      xar = brz0v; xar = MFMA(wx[0][0], ax, xar);                        \
      xaz = brz1v; xaz = MFMA(wx[0][1], ax, xaz);                        \
      xan = binv;  xan = MFMA(wx[0][2], ax, xan);                        \
    } else {                                                             \
      if (DO1) {                                                         \
        f32x4 gr = arx + arh, gz = azx + azh;                            \
        half4 pk = gate_upd(gr, gz, anx, anh, hst);                      \
        *(half4*)(arena + 2 * BUFE + (WO) + wroff) = pk;                 \
      }                                                                  \
      const _Float16* s1n = arena + (WO) + rdoff;   /* h1[I] preload */  \
      bx0 = *(const half8*)s1n;                                          \
      bx1 = *(const half8*)(s1n + 32);                                   \
    }                                                                    \
    BARRIER();                                                           \
  } while (0)

    // region 0: grp0 computes h1[0] (h-side reads zeroed buf); grp1 preloads
    REGION(0, BUFE, 0, x1a, x1b, 0);
    for (int i = 1; i + 1 < Tlen; i += 2) {
        REGION(i,     0,    BUFE, x0a, x0b, 1);
        REGION(i + 1, BUFE, 0,    x1a, x1b, 1);
    }
    REGION(Tlen - 1, 0, BUFE, x0a, x0b, 1);
#undef REGION

    // ---- epilogue: grp1 step J = 511 (MFMA + gates, no h2 writeback) ----
    if (grp == 1) {
        const _Float16* s2 = arena + 2 * BUFE + BUFE + rdoff;   // h2[510]
        half8 bh0 = *(const half8*)s2;
        half8 bh1 = *(const half8*)(s2 + 32);
        f32x4 arx2 = brz0v, azx2 = brz1v, anx2 = binv;
        f32x4 arh2 = {0.f,0.f,0.f,0.f}, azh2 = {0.f,0.f,0.f,0.f}, anh2 = bhnv;
        arx2 = MFMA(wx[0][0], bx0, arx2); arx2 = MFMA(wx[1][0], bx1, arx2);
        azx2 = MFMA(wx[0][1], bx0, azx2); azx2 = MFMA(wx[1][1], bx1, azx2);
        anx2 = MFMA(wx[0][2], bx0, anx2); anx2 = MFMA(wx[1][2], bx1, anx2);
        arh2 = MFMA(wh[0][0], bh0, arh2); arh2 = MFMA(wh[1][0], bh1, arh2);
        azh2 = MFMA(wh[0][1], bh0, azh2); azh2 = MFMA(wh[1][1], bh1, azh2);
        anh2 = MFMA(wh[0][2], bh0, anh2); anh2 = MFMA(wh[1][2], bh1, anh2);
        f32x4 gr = arx2 + arh2, gz = azx2 + azh2;
        gate_upd(gr, gz, anx2, anh2, hst);
        f32x4 fv;
#pragma unroll
        for (int r = 0; r < 4; ++r) fv[r] = hst[r];
        *(f32x4*)(&hfin[m][gc]) = fv;              // batch m, cols gc..gc+3
    }
    __syncthreads();
    if (tid < BT) {                                // FC head
        float acc = fcb[0];
        for (int c = 0; c < Hd; ++c) acc += hfin[tid][c] * fcw[c];
        out[b0 + tid] = acc;
    }
}

extern "C" void kernel_launch(void* const* d_in, const int* in_sizes, int n_in,
                              void* d_out, int out_size, void* d_ws, size_t ws_size,
                              hipStream_t stream) {
    gru_fused<<<dim3(Bsz / BT), dim3(512), 0, stream>>>(
        (const float*)d_in[0],
        (const float*)d_in[1], (const float*)d_in[2],
        (const float*)d_in[3], (const float*)d_in[4],
        (const float*)d_in[5], (const float*)d_in[6],
        (const float*)d_in[7], (const float*)d_in[8],
        (const float*)d_in[9], (const float*)d_in[10],
        (float*)d_out);
}

// Round 9
// 464.178 us; speedup vs baseline: 5.1427x; 1.0504x over previous
//
#include <hip/hip_runtime.h>

#define Bsz  2048
#define Tlen 512
#define Din  32
#define Hd   64
#define BT   16            // batches per block (MFMA N=16)
#define HS   72            // h row stride in f16 elems (144B, 16B-aligned, bank-spread)
#define BUFE 2048          // f16 elems per h buffer (4096 B)

typedef _Float16 half8 __attribute__((ext_vector_type(8)));
typedef _Float16 half4 __attribute__((ext_vector_type(4)));
typedef float    f32x4 __attribute__((ext_vector_type(4)));

#define MFMA(a, b, c) __builtin_amdgcn_mfma_f32_16x16x32_f16((a), (b), (c), 0, 0, 0)

// lgkm-only barrier: orders LDS producer->consumer across waves WITHOUT
// draining vmcnt -- the x global prefetch loads stay in flight across
// barriers ("memory" clobber stops compiler reordering memory ops across).
#define BARRIER()                                              \
  do {                                                         \
    asm volatile("s_waitcnt lgkmcnt(0)" ::: "memory");         \
    __builtin_amdgcn_s_barrier();                              \
  } while (0)

__device__ __forceinline__ half8 load8s(const float* p, float s) {
    half8 r;
#pragma unroll
    for (int j = 0; j < 8; ++j) r[j] = (_Float16)(p[j] * s);
    return r;
}
__device__ __forceinline__ half8 cvt8(float4 a, float4 b) {
    half8 r;
    r[0] = (_Float16)a.x; r[1] = (_Float16)a.y; r[2] = (_Float16)a.z; r[3] = (_Float16)a.w;
    r[4] = (_Float16)b.x; r[5] = (_Float16)b.y; r[6] = (_Float16)b.z; r[7] = (_Float16)b.w;
    return r;
}

// weights pre-scaled by -log2(e) (r,z) and -2*log2(e) (n). With E = 2^(scaled):
//   sigma(raw) = 1/(1+E),  tanh(raw_n) = (1-E_n)/(1+E_n)
// GRU update folds to ONE rcp:  h' = [E_z(1-E_n) + h(1+E_n)] / [(1+E_z)(1+E_n)]
__device__ __forceinline__ half4 gate_upd(const f32x4& gr, const f32x4& gz,
                                          const f32x4& anx, const f32x4& anh,
                                          float hst[4]) {
    half4 pk;
#pragma unroll
    for (int r = 0; r < 4; ++r) {
        float Er = __builtin_amdgcn_exp2f(gr[r]);
        float rr = __builtin_amdgcn_rcpf(1.0f + Er);
        float yy = anx[r] + rr * anh[r];
        float En = __builtin_amdgcn_exp2f(yy);
        float Ez = __builtin_amdgcn_exp2f(gz[r]);
        float num = Ez * (1.0f - En) + hst[r] * (1.0f + En);
        float den = (1.0f + Ez) * (1.0f + En);
        hst[r] = num * __builtin_amdgcn_rcpf(den);
        pk[r] = (_Float16)hst[r];
    }
    return pk;
}

// ===========================================================================
// Refined mono GRU: 128 blocks x 512 threads; waves 0-3 = layer 1 (grp0),
// waves 4-7 = layer 2 (grp1). ONE lgkm-only barrier per step (the measured
// sync-cost minimum: 2nd barrier = +273 cy/step [r8], LDS flags = +500 [r6],
// cross-block = +50x [r5]).
// Region I:
//  grp0: read h1[I-1]@RO (2x b128), 6 h-MFMA, gates using PRECOMPUTED x-side
//        acc (xar/xaz/xan), write h1[I]@WO;
//        then (pre-barrier slack, off next chain): cvt8 x[I+1] + 3 x-MFMA ->
//        xacc for region I+1; refill parity regs with x[I+3] (global, stays
//        in flight across barriers).
//  grp1: read h1[I-1]@RO + h2[I-2]@2B+RO (4x b128), 12 MFMA, gates,
//        write h2[I-1]@2B+WO.   [the long pole that grp0's tail hides under]
// Arena zero-init makes region 0 and 1 exact (h-side MFMAs on zeros = bias).
// Same arithmetic as r1-mono at identical rounding points.
// ===========================================================================
__global__ __launch_bounds__(512)
void gru_fused(const float* __restrict__ x,
               const float* __restrict__ Wih0, const float* __restrict__ Whh0,
               const float* __restrict__ bih0, const float* __restrict__ bhh0,
               const float* __restrict__ Wih1, const float* __restrict__ Whh1,
               const float* __restrict__ bih1, const float* __restrict__ bhh1,
               const float* __restrict__ fcw,  const float* __restrict__ fcb,
               float* __restrict__ out)
{
    __shared__ _Float16 arena[4 * BUFE];   // h1 @[0],[B]; h2 @[2B],[3B]
    __shared__ float hfin[BT][Hd];

    const int tid  = threadIdx.x;
    const int lane = tid & 63;
    const int wave = tid >> 6;
    const int grp  = wave >> 2;            // 0 = layer1, 1 = layer2
    const int wg   = wave & 3;             // 16 gate-cols per wave
    const int m    = lane & 15;            // A row (W row) AND B col (batch)
    const int quad = lane >> 4;            // k-chunk (A/B), col-group (C/D)
    const int col  = (wg << 4) + m;        // W row this lane loads (A-frag)
    const int gc   = (wg << 4) + (quad << 2); // C-frag col base this lane owns
    const int b0   = blockIdx.x << 4;

    for (int idx = tid; idx < 4 * BUFE; idx += 512) arena[idx] = (_Float16)0.f;

    const float sRZ = -1.44269504f;        // -log2(e)
    const float sN  = -2.88539008f;        // -2*log2(e)
    const int rdoff = m * HS + quad * 8;   // B-frag read: batch m, k = quad*8..
    const int wroff = m * HS + gc;         // C write: batch m, cols gc..gc+3
    float hst[4] = {0.f, 0.f, 0.f, 0.f};

    // ---- persistent pre-scaled weight A-fragments + biases ----
    half8 wx[2][3], wh[2][3];
    f32x4 brz0v, brz1v, binv, bhnv;
    if (grp == 0) {
        wx[0][0] = load8s(Wih0 + (      col) * Din + quad * 8, sRZ);
        wx[0][1] = load8s(Wih0 + ( 64 + col) * Din + quad * 8, sRZ);
        wx[0][2] = load8s(Wih0 + (128 + col) * Din + quad * 8, sN);
#pragma unroll
        for (int kb = 0; kb < 2; ++kb) {
            wh[kb][0] = load8s(Whh0 + (      col) * Hd + kb * 32 + quad * 8, sRZ);
            wh[kb][1] = load8s(Whh0 + ( 64 + col) * Hd + kb * 32 + quad * 8, sRZ);
            wh[kb][2] = load8s(Whh0 + (128 + col) * Hd + kb * 32 + quad * 8, sN);
        }
#pragma unroll
        for (int r = 0; r < 4; ++r) {
            brz0v[r] = sRZ * (bih0[gc + r] + bhh0[gc + r]);
            brz1v[r] = sRZ * (bih0[64 + gc + r] + bhh0[64 + gc + r]);
            binv[r]  = sN * bih0[128 + gc + r];
            bhnv[r]  = sN * bhh0[128 + gc + r];
        }
    } else {
#pragma unroll
        for (int kb = 0; kb < 2; ++kb) {
            wx[kb][0] = load8s(Wih1 + (      col) * Hd + kb * 32 + quad * 8, sRZ);
            wx[kb][1] = load8s(Wih1 + ( 64 + col) * Hd + kb * 32 + quad * 8, sRZ);
            wx[kb][2] = load8s(Wih1 + (128 + col) * Hd + kb * 32 + quad * 8, sN);
            wh[kb][0] = load8s(Whh1 + (      col) * Hd + kb * 32 + quad * 8, sRZ);
            wh[kb][1] = load8s(Whh1 + ( 64 + col) * Hd + kb * 32 + quad * 8, sRZ);
            wh[kb][2] = load8s(Whh1 + (128 + col) * Hd + kb * 32 + quad * 8, sN);
        }
#pragma unroll
        for (int r = 0; r < 4; ++r) {
            brz0v[r] = sRZ * (bih1[gc + r] + bhh1[gc + r]);
            brz1v[r] = sRZ * (bih1[64 + gc + r] + bhh1[64 + gc + r]);
            binv[r]  = sN * bih1[128 + gc + r];
            bhnv[r]  = sN * bhh1[128 + gc + r];
        }
    }

    // ---- grp0 pipeline state: x parity prefetch + precomputed x-side acc ----
    // Region I consumes parity (I+1)&1 (holding x[I+1]) and refills it with
    // x[I+3]. Init: xacc <- x[0]; parity1 <- x[1]; parity0 <- x[2].
    const float* xgp = x + (size_t)(b0 + m) * (Tlen * Din) + quad * 8;
    float4 x0a, x0b, x1a, x1b;
    f32x4 xar, xaz, xan;                   // x-side acc (incl. biases) for region I
    if (grp == 0) {
        float4 xia = *(const float4*)(xgp), xib = *(const float4*)(xgp + 4);
        x1a = *(const float4*)(xgp + Din);      x1b = *(const float4*)(xgp + Din + 4);
        x0a = *(const float4*)(xgp + 2 * Din);  x0b = *(const float4*)(xgp + 2 * Din + 4);
        half8 ax = cvt8(xia, xib);          // x[0]
        xar = brz0v; xar = MFMA(wx[0][0], ax, xar);
        xaz = brz1v; xaz = MFMA(wx[0][1], ax, xaz);
        xan = binv;  xan = MFMA(wx[0][2], ax, xan);
    }

    __syncthreads();                       // arena zero + weights visible

// Region I. RO/WO compile-time buffer offsets. XA/XB: parity regs holding
// x[I+1] (consumed, then refilled with x[I+3]). DO1: grp1 active (I >= 1).
#define REGION(I, RO, WO, XA, XB, DO1)                                   \
  do {                                                                   \
    if (grp == 0) {                                                      \
      const _Float16* s1 = arena + (RO) + rdoff;                         \
      half8 bh0 = *(const half8*)s1;                                     \
      half8 bh1 = *(const half8*)(s1 + 32);                              \
      f32x4 arh0 = {0.f,0.f,0.f,0.f}, azh0 = {0.f,0.f,0.f,0.f};          \
      f32x4 anh0 = bhnv;                                                 \
      arh0 = MFMA(wh[0][0], bh0, arh0); arh0 = MFMA(wh[1][0], bh1, arh0);\
      azh0 = MFMA(wh[0][1], bh0, azh0); azh0 = MFMA(wh[1][1], bh1, azh0);\
      anh0 = MFMA(wh[0][2], bh0, anh0); anh0 = MFMA(wh[1][2], bh1, anh0);\
      f32x4 gr = xar + arh0, gz = xaz + azh0;                            \
      half4 pk = gate_upd(gr, gz, xan, anh0, hst);                       \
      *(half4*)(arena + (WO) + wroff) = pk;                              \
      /* pre-barrier slack: xacc for region I+1 + parity refill x[I+3] */\
      half8 ax = cvt8(XA, XB);             /* x[I+1] */                  \
      { const int nx = ((I) + 3 < Tlen) ? (I) + 3 : Tlen - 1;            \
        const float* p = xgp + (size_t)nx * Din;                         \
        XA = *(const float4*)p; XB = *(const float4*)(p + 4); }          \
      xar = brz0v; xar = MFMA(wx[0][0], ax, xar);                        \
      xaz = brz1v; xaz = MFMA(wx[0][1], ax, xaz);                        \
      xan = binv;  xan = MFMA(wx[0][2], ax, xan);                        \
    } else if (DO1) {                                                    \
      const _Float16* s1 = arena + (RO) + rdoff;            /* h1[I-1] */\
      const _Float16* s2 = s1 + 2 * BUFE;                   /* h2[I-2] */\
      half8 bx0 = *(const half8*)s1;                                     \
      half8 bx1 = *(const half8*)(s1 + 32);                              \
      half8 bh0 = *(const half8*)s2;                                     \
      half8 bh1 = *(const half8*)(s2 + 32);                              \
      f32x4 arx = brz0v, azx = brz1v, anx = binv;                        \
      f32x4 arh = {0.f,0.f,0.f,0.f}, azh = {0.f,0.f,0.f,0.f};            \
      f32x4 anh = bhnv;                                                  \
      arx = MFMA(wx[0][0], bx0, arx); arx = MFMA(wx[1][0], bx1, arx);    \
      azx = MFMA(wx[0][1], bx0, azx); azx = MFMA(wx[1][1], bx1, azx);    \
      anx = MFMA(wx[0][2], bx0, anx); anx = MFMA(wx[1][2], bx1, anx);    \
      arh = MFMA(wh[0][0], bh0, arh); arh = MFMA(wh[1][0], bh1, arh);    \
      azh = MFMA(wh[0][1], bh0, azh); azh = MFMA(wh[1][1], bh1, azh);    \
      anh = MFMA(wh[0][2], bh0, anh); anh = MFMA(wh[1][2], bh1, anh);    \
      f32x4 gr = arx + arh, gz = azx + azh;                              \
      half4 pk = gate_upd(gr, gz, anx, anh, hst);                        \
      *(half4*)(arena + 2 * BUFE + (WO) + wroff) = pk;                   \
    }                                                                    \
    BARRIER();                                                           \
  } while (0)

    // region 0: grp0 computes h1[0] (h-side reads zeroed buf @BUFE); grp1 idle
    REGION(0, BUFE, 0, x1a, x1b, 0);
    // main: regions 1..510 (region I consumes parity (I+1)&1)
    for (int i = 1; i + 1 < Tlen; i += 2) {
        REGION(i,     0,    BUFE, x0a, x0b, 1);    // I odd:  x[I+1] even -> p0
        REGION(i + 1, BUFE, 0,    x1a, x1b, 1);    // I even: x[I+1] odd  -> p1
    }
    REGION(Tlen - 1, 0, BUFE, x0a, x0b, 1);        // region 511

    // ---- epilogue: grp1 step 511 (reads h1[511]@BUFE, h2[510]@2B+BUFE) ----
    if (grp == 1) {
        const _Float16* s1 = arena + BUFE + rdoff;
        const _Float16* s2 = s1 + 2 * BUFE;
        half8 bx0 = *(const half8*)s1;
        half8 bx1 = *(const half8*)(s1 + 32);
        half8 bh0 = *(const half8*)s2;
        half8 bh1 = *(const half8*)(s2 + 32);
        f32x4 arx = brz0v, azx = brz1v, anx = binv;
        f32x4 arh = {0.f,0.f,0.f,0.f}, azh = {0.f,0.f,0.f,0.f}, anh = bhnv;
        arx = MFMA(wx[0][0], bx0, arx); arx = MFMA(wx[1][0], bx1, arx);
        azx = MFMA(wx[0][1], bx0, azx); azx = MFMA(wx[1][1], bx1, azx);
        anx = MFMA(wx[0][2], bx0, anx); anx = MFMA(wx[1][2], bx1, anx);
        arh = MFMA(wh[0][0], bh0, arh); arh = MFMA(wh[1][0], bh1, arh);
        azh = MFMA(wh[0][1], bh0, azh); azh = MFMA(wh[1][1], bh1, azh);
        anh = MFMA(wh[0][2], bh0, anh); anh = MFMA(wh[1][2], bh1, anh);
        f32x4 gr = arx + arh, gz = azx + azh;
        gate_upd(gr, gz, anx, anh, hst);
        f32x4 fv;
#pragma unroll
        for (int r = 0; r < 4; ++r) fv[r] = hst[r];
        *(f32x4*)(&hfin[m][gc]) = fv;              // batch m, cols gc..gc+3
    }
    __syncthreads();
    if (tid < BT) {                                // FC head
        float acc = fcb[0];
        for (int c = 0; c < Hd; ++c) acc += hfin[tid][c] * fcw[c];
        out[b0 + tid] = acc;
    }
#undef REGION
}

extern "C" void kernel_launch(void* const* d_in, const int* in_sizes, int n_in,
                              void* d_out, int out_size, void* d_ws, size_t ws_size,
                              hipStream_t stream) {
    gru_fused<<<dim3(Bsz / BT), dim3(512), 0, stream>>>(
        (const float*)d_in[0],
        (const float*)d_in[1], (const float*)d_in[2],
        (const float*)d_in[3], (const float*)d_in[4],
        (const float*)d_in[5], (const float*)d_in[6],
        (const float*)d_in[7], (const float*)d_in[8],
        (const float*)d_in[9], (const float*)d_in[10],
        (float*)d_out);
}